// Round 1
// baseline (213.897 us; speedup 1.0000x reference)
//
#include <hip/hip_runtime.h>
#include <hip/hip_bf16.h>

// SupCon loss, N=8192, D=128, T=0.1.
// R6: 2 nodes (was 3). Timing analysis: ~82us of the 98.6us budget is the
// harness's two 256MiB workspace-poison fills (fillBufferAligned @41us,
// WRITE_SIZE=262144KB each) -- not addressable from the kernel. Remaining
// ~16us is ours. This round: (a) finalize fused into supcon_main via a
// device-scope completion counter (last of 2080 blocks computes the loss
// sum; saves one launch + one graph gap), (b) row-side se[16] reduction
// moved from 80 ds_swizzle ops/wave (shared DS pipe) to VALU DPP
// (row_shr 1/2/4/8 + row_bcast:15; half-sums land in lanes 31/63).
//
// Math: loss_i = (cm1_i*lse_i - 10*(cd_i - sd_i))/(cm1_i+tiny)
//   lse_i = 10 + ln(sum_{j!=i} e^{s_ij-10})  (constant shift exact; s<=10)
//   cd_i = x_i . classsum[lab_i], sd_i = x_i . x_i (bf16-rounded inputs,
//   consistent with the MFMA path). se accumulated INCLUDING diagonal;
//   diag e^{10*sd-10} subtracted in finalize.
//   Symmetry: tile (I,ct), ct>I feeds rows AND cols; ct==I rows only.

typedef __bf16 bf16_t;
typedef __bf16 bf16x2 __attribute__((ext_vector_type(2)));
typedef __bf16 bf16x8 __attribute__((ext_vector_type(8)));
typedef float f32x16 __attribute__((ext_vector_type(16)));

#define NN 8192
#define DIM 128
#define MAIN_BLOCKS 2080          // sum_{cq=0}^{63} (cq+1)
#define SMALL_VAL 1.17549435e-38f
#define L2E10 14.4269504089f      // 10*log2(e)
#define LN2 0.69314718056f

// Swizzle: X[row][d] at (row>>5)*4096 + (d>>4)*512 + ((d>>3)&1)*256 + (row&31)*8 + (d&7)
// Lane l holds dims (2l, 2l+1): f=l>>3, hh=(l>>2)&1, j=(l&3)*2 (pair contiguous).
__device__ inline size_t swz(int row, int lane) {
    int f = lane >> 3, hh = (lane >> 2) & 1, j = (lane & 3) << 1;
    return ((size_t)(row >> 5) * 4096) + f * 512 + hh * 256 + (row & 31) * 8 + j;
}

// DPP-add step: v += dpp_perm(v). old=0 + bound_ctrl=1 so disabled/invalid
// lanes contribute 0 to the add. ctrl/rmask must be ICEs -> macro.
#define DPPADD(v, ctrl, rmask)                                                         \
    do {                                                                               \
        int _t = __builtin_amdgcn_update_dpp(0, __float_as_int((v)), (ctrl), (rmask),  \
                                             0xf, true);                               \
        (v) += __int_as_float(_t);                                                     \
    } while (0)

// Sum over each 32-lane half; result valid in lane 31 (h=0) and lane 63 (h=1).
__device__ inline float half32_sum(float v) {
    DPPADD(v, 0x111, 0xf);   // row_shr:1
    DPPADD(v, 0x112, 0xf);   // row_shr:2
    DPPADD(v, 0x114, 0xf);   // row_shr:4
    DPPADD(v, 0x118, 0xf);   // row_shr:8  -> lane 15+16k has 16-lane row sum
    DPPADD(v, 0x142, 0xa);   // row_bcast:15 into rows 1,3 -> lanes 31/63 full
    return v;
}

// --- fused normalize + class-sum + per-row finalize scalars ---
__global__ __launch_bounds__(256) void norm_csum(const float* __restrict__ emb,
                                                 const int* __restrict__ labels,
                                                 bf16_t* __restrict__ xsw,
                                                 float* __restrict__ cd_arr,
                                                 float* __restrict__ sd_arr,
                                                 float* __restrict__ cm1_arr,
                                                 float* __restrict__ se_acc,
                                                 int* __restrict__ done_cnt) {
    __shared__ float cs[DIM];
    __shared__ int rowlist[96];
    __shared__ int nrows;
    int cls = blockIdx.x;                      // 1024 blocks; labels < 1000
    int wv = threadIdx.x >> 6, lane = threadIdx.x & 63;
    if (threadIdx.x < DIM) cs[threadIdx.x] = 0.f;
    if (threadIdx.x == 0) nrows = 0;
    if (threadIdx.x < 8) se_acc[cls * 8 + threadIdx.x] = 0.f;   // zero all 8192
    if (cls == 0 && threadIdx.x == 0) *done_cnt = 0;            // ws is poisoned
    __syncthreads();

    float s0 = 0.f, s1 = 0.f;
    const int4* lab4 = (const int4*)(labels + wv * 2048);       // wave's quarter
#pragma unroll
    for (int it = 0; it < 8; ++it) {
        int4 l = lab4[it * 64 + lane];
        int base = wv * 2048 + it * 256;
#pragma unroll
        for (int cmp = 0; cmp < 4; ++cmp) {
            int li = (cmp == 0) ? l.x : (cmp == 1) ? l.y : (cmp == 2) ? l.z : l.w;
            unsigned long long m = __ballot(li == cls);
            while (m) {                         // wave-uniform loop, ~2 rows/wave avg
                int bb = __builtin_ctzll(m);
                m &= m - 1;
                int row = base + 4 * bb + cmp;
                float2 v = ((const float2*)emb)[row * 64 + lane];
                float ss = fmaf(v.x, v.x, v.y * v.y);
#pragma unroll
                for (int mm = 1; mm < 64; mm <<= 1) ss += __shfl_xor(ss, mm, 64);
                float inv = 1.0f / fmaxf(sqrtf(ss), 1e-12f);
                bf16x2 o; o.x = (bf16_t)(v.x * inv); o.y = (bf16_t)(v.y * inv);
                *(bf16x2*)(xsw + swz(row, lane)) = o;
                s0 += (float)o.x; s1 += (float)o.y;     // bf16-rounded, matches MFMA
                if (lane == 0) {
                    int idx = atomicAdd(&nrows, 1);
                    if (idx < 96) rowlist[idx] = row;
                }
            }
        }
    }
    atomicAdd(&cs[2 * lane], s0);
    atomicAdd(&cs[2 * lane + 1], s1);
    __syncthreads();
    int n = nrows;
    for (int k = wv; k < n; k += 4) {          // per-row cd/sd (rows split over waves)
        int row = rowlist[k];
        bf16x2 xv = *(const bf16x2*)(xsw + swz(row, lane));
        float x0 = (float)xv.x, x1 = (float)xv.y;
        float cdp = fmaf(x0, cs[2 * lane], x1 * cs[2 * lane + 1]);
        float sdp = fmaf(x0, x0, x1 * x1);
#pragma unroll
        for (int mm = 1; mm < 64; mm <<= 1) {
            cdp += __shfl_xor(cdp, mm, 64);
            sdp += __shfl_xor(sdp, mm, 64);
        }
        if (lane == 0) {
            cd_arr[row] = cdp; sd_arr[row] = sdp; cm1_arr[row] = (float)(n - 1);
        }
    }
}

// --- main: block = (cq, g): 128-col chunk staged to LDS once; wave wv -> row
// band I = 4g+wv (I <= 4cq+3). C layout (m74/m101): col = lane&31,
// row = (r&3) + 8*(r>>2) + 4*(lane>>5).
// Last block to finish (device completion counter) runs the finalize pass.
__global__ __launch_bounds__(256, 4) void supcon_main(const bf16_t* __restrict__ xsw,
                                                      float* __restrict__ se_acc,
                                                      const float* __restrict__ cd_arr,
                                                      const float* __restrict__ sd_arr,
                                                      const float* __restrict__ cm1_arr,
                                                      int* __restrict__ done_cnt,
                                                      float* __restrict__ out) {
    __shared__ bf16_t bst[4 * 4096];           // 32 KB: the 4 shared B tiles
    __shared__ float cols[128];
    __shared__ int lastflag;
    __shared__ float part[4];
    if (threadIdx.x < 128) cols[threadIdx.x] = 0.f;

    int b = blockIdx.x;                        // triangular decode
    int cq = (int)((sqrtf(8.f * (float)b + 1.f) - 1.f) * 0.5f);
    while ((cq + 1) * (cq + 2) / 2 <= b) ++cq;
    while (cq * (cq + 1) / 2 > b) --cq;
    int g = b - cq * (cq + 1) / 2;

    int wv = threadIdx.x >> 6, lane = threadIdx.x & 63;
    int I = 4 * g + wv;
    int c = lane & 31, h = lane >> 5;
    int laneoff = h * 256 + c * 8;

    // A frags (global, per wave) — issued before staging so latencies overlap
    const bf16_t* abase = xsw + (size_t)I * 4096 + laneoff;
    bf16x8 a[8];
#pragma unroll
    for (int f = 0; f < 8; ++f) a[f] = *(const bf16x8*)(abase + f * 512);

    // stage B chunk (32 KB) once for all 4 waves
    {
        const uint4* gsrc = (const uint4*)(xsw + (size_t)cq * 4 * 4096);
        uint4* ldst = (uint4*)bst;
#pragma unroll
        for (int i = 0; i < 8; ++i)
            ldst[i * 256 + threadIdx.x] = gsrc[i * 256 + threadIdx.x];
    }
    __syncthreads();

    float se[16];
#pragma unroll
    for (int r = 0; r < 16; ++r) se[r] = 0.f;
    float colacc[4] = {0.f, 0.f, 0.f, 0.f};

#pragma unroll
    for (int t = 0; t < 4; ++t) {
        const bf16_t* bt = bst + t * 4096 + laneoff;
        bf16x8 bfr[8];
#pragma unroll
        for (int f = 0; f < 8; ++f) bfr[f] = *(const bf16x8*)(bt + f * 512);
        f32x16 acc;
#pragma unroll
        for (int r = 0; r < 16; ++r) acc[r] = 0.f;
#pragma unroll
        for (int f = 0; f < 8; ++f)
            acc = __builtin_amdgcn_mfma_f32_32x32x16_bf16(a[f], bfr[f], acc, 0, 0, 0);
        int ct = cq * 4 + t;
        if (ct >= I) {                          // wave-uniform mask
            float c0 = 0.f, c1 = 0.f, c2 = 0.f, c3 = 0.f;
#pragma unroll
            for (int r = 0; r < 16; ++r) {
                float e = __builtin_amdgcn_exp2f(fmaf(acc[r], L2E10, -L2E10));
                se[r] += e;
                if ((r & 3) == 0) c0 += e; else if ((r & 3) == 1) c1 += e;
                else if ((r & 3) == 2) c2 += e; else c3 += e;
            }
            if (ct > I) colacc[t] = (c0 + c1) + (c2 + c3);
        }
    }

    // row-side: DPP half-wave reduce (VALU pipe, not DS); sums land in lanes
    // 31 (h=0) and 63 (h=1), which emit the atomics.
#pragma unroll
    for (int r = 0; r < 16; ++r) se[r] = half32_sum(se[r]);
    if (c == 31) {
        int rowbase = I * 32 + 4 * h;
#pragma unroll
        for (int r = 0; r < 16; ++r)
            atomicAdd(&se_acc[rowbase + (r & 3) + 8 * (r >> 2)], se[r]);
    }

    // col-side: combine halves, LDS-combine 4 waves (same cq), flush once
#pragma unroll
    for (int t = 0; t < 4; ++t) {
        float v = colacc[t] + __shfl_xor(colacc[t], 32, 64);
        if (h == 0) atomicAdd(&cols[t * 32 + c], v);
    }
    __syncthreads();
    if (threadIdx.x < 128)
        atomicAdd(&se_acc[cq * 128 + threadIdx.x], cols[threadIdx.x]);

    // ---- fused finalize: last block to retire computes the loss sum ----
    __threadfence();                           // publish my atomics (all threads)
    __syncthreads();
    if (threadIdx.x == 0) {
        int prev = atomicAdd(done_cnt, 1);
        lastflag = (prev == MAIN_BLOCKS - 1) ? 1 : 0;
    }
    __syncthreads();
    if (lastflag == 0) return;
    __threadfence();                           // acquire everyone's atomics

    float total = 0.f;
#pragma unroll 4
    for (int k = 0; k < 32; ++k) {
        int i = (k << 8) + threadIdx.x;        // coalesced
        float sd = sd_arr[i], cd = cd_arr[i], cm1 = cm1_arr[i];
        float diag = __builtin_amdgcn_exp2f(fmaf(sd, L2E10, -L2E10));
        float sev  = fmaxf(se_acc[i] - diag, 1e-30f);
        float lse  = fmaf(__builtin_amdgcn_logf(sev), LN2, 10.f);   // v_log = log2
        total += (cm1 * lse - 10.f * (cd - sd)) / (cm1 + SMALL_VAL);
    }
#pragma unroll
    for (int m = 1; m < 64; m <<= 1) total += __shfl_xor(total, m, 64);
    if (lane == 0) part[wv] = total;
    __syncthreads();
    if (threadIdx.x == 0) *out = part[0] + part[1] + part[2] + part[3];
}

extern "C" void kernel_launch(void* const* d_in, const int* in_sizes, int n_in,
                              void* d_out, int out_size, void* d_ws, size_t ws_size,
                              hipStream_t stream) {
    const float* emb  = (const float*)d_in[0];
    const int* labels = (const int*)d_in[1];

    char* ws = (char*)d_ws;
    bf16_t* xsw = (bf16_t*)ws;                          // 2 MB swizzled normalized X
    float* se   = (float*)(ws + (size_t)NN * DIM * 2);  // 32 KB
    float* cd   = se + NN;                              // 32 KB
    float* sd   = cd + NN;                              // 32 KB
    float* cm1  = sd + NN;                              // 32 KB
    int* done   = (int*)(cm1 + NN);                     // 4 B completion counter

    norm_csum<<<1024, 256, 0, stream>>>(emb, labels, xsw, cd, sd, cm1, se, done);
    supcon_main<<<MAIN_BLOCKS, 256, 0, stream>>>(xsw, se, cd, sd, cm1, done, (float*)d_out);
}

// Round 3
// 112.950 us; speedup vs baseline: 1.8937x; 1.8937x over previous
//
#include <hip/hip_runtime.h>
#include <hip/hip_bf16.h>

// SupCon loss, N=8192, D=128, T=0.1.
// R8 == R7 resubmitted verbatim (round-2 bench died with "container failed
// twice" -- infra signature: no pytest output, no profile; R6 with the SAME
// fused structure + heavier fences ran and passed. No control path here can
// hang: no spins, no grid barrier; every block bumps done_cnt once and
// exits or runs a bounded finalize).
//
// R7 rationale: R6's per-block __threadfence() (agent-scope seq_cst) emits
// L2 writeback/invalidate on gfx950 (non-coherent per-XCD L2s); 2080 blocks
// x 2 fences serialized in the L2 queues = ~148us. The fences are
// unnecessary: all cross-block values are device-scope global atomicAdds
// (performed at the coherent point), and __syncthreads() drains vmcnt(0)
// before s_barrier, so completion ordering is already guaranteed before the
// done_cnt increment. Final block reads se_acc via relaxed agent-scope
// atomic loads (cache-bypassing) + ONE acquire fence.
//
// Math: loss_i = (cm1_i*lse_i - 10*(cd_i - sd_i))/(cm1_i+tiny)
//   lse_i = 10 + ln(sum_{j!=i} e^{s_ij-10})  (constant shift exact; s<=10)
//   cd_i = x_i . classsum[lab_i], sd_i = x_i . x_i (bf16-rounded inputs,
//   consistent with the MFMA path). se accumulated INCLUDING diagonal;
//   diag e^{10*sd-10} subtracted in finalize.
//   Symmetry: tile (I,ct), ct>I feeds rows AND cols; ct==I rows only.

typedef __bf16 bf16_t;
typedef __bf16 bf16x2 __attribute__((ext_vector_type(2)));
typedef __bf16 bf16x8 __attribute__((ext_vector_type(8)));
typedef float f32x16 __attribute__((ext_vector_type(16)));

#define NN 8192
#define DIM 128
#define MAIN_BLOCKS 2080          // sum_{cq=0}^{63} (cq+1)
#define SMALL_VAL 1.17549435e-38f
#define L2E10 14.4269504089f      // 10*log2(e)
#define LN2 0.69314718056f

// Swizzle: X[row][d] at (row>>5)*4096 + (d>>4)*512 + ((d>>3)&1)*256 + (row&31)*8 + (d&7)
// Lane l holds dims (2l, 2l+1): f=l>>3, hh=(l>>2)&1, j=(l&3)*2 (pair contiguous).
__device__ inline size_t swz(int row, int lane) {
    int f = lane >> 3, hh = (lane >> 2) & 1, j = (lane & 3) << 1;
    return ((size_t)(row >> 5) * 4096) + f * 512 + hh * 256 + (row & 31) * 8 + j;
}

// DPP-add step: v += dpp_perm(v). old=0 + bound_ctrl=1 so disabled/invalid
// lanes contribute 0 to the add. ctrl/rmask must be ICEs -> macro.
#define DPPADD(v, ctrl, rmask)                                                         \
    do {                                                                               \
        int _t = __builtin_amdgcn_update_dpp(0, __float_as_int((v)), (ctrl), (rmask),  \
                                             0xf, true);                               \
        (v) += __int_as_float(_t);                                                     \
    } while (0)

// Sum over each 32-lane half; result valid in lane 31 (h=0) and lane 63 (h=1).
__device__ inline float half32_sum(float v) {
    DPPADD(v, 0x111, 0xf);   // row_shr:1
    DPPADD(v, 0x112, 0xf);   // row_shr:2
    DPPADD(v, 0x114, 0xf);   // row_shr:4
    DPPADD(v, 0x118, 0xf);   // row_shr:8  -> lane 15+16k has 16-lane row sum
    DPPADD(v, 0x142, 0xa);   // row_bcast:15 into rows 1,3 -> lanes 31/63 full
    return v;
}

// --- fused normalize + class-sum + per-row finalize scalars ---
__global__ __launch_bounds__(256) void norm_csum(const float* __restrict__ emb,
                                                 const int* __restrict__ labels,
                                                 bf16_t* __restrict__ xsw,
                                                 float* __restrict__ cd_arr,
                                                 float* __restrict__ sd_arr,
                                                 float* __restrict__ cm1_arr,
                                                 float* __restrict__ se_acc,
                                                 int* __restrict__ done_cnt) {
    __shared__ float cs[DIM];
    __shared__ int rowlist[96];
    __shared__ int nrows;
    int cls = blockIdx.x;                      // 1024 blocks; labels < 1000
    int wv = threadIdx.x >> 6, lane = threadIdx.x & 63;
    if (threadIdx.x < DIM) cs[threadIdx.x] = 0.f;
    if (threadIdx.x == 0) nrows = 0;
    if (threadIdx.x < 8) se_acc[cls * 8 + threadIdx.x] = 0.f;   // zero all 8192
    if (cls == 0 && threadIdx.x == 0) *done_cnt = 0;            // ws is poisoned
    __syncthreads();

    float s0 = 0.f, s1 = 0.f;
    const int4* lab4 = (const int4*)(labels + wv * 2048);       // wave's quarter
#pragma unroll
    for (int it = 0; it < 8; ++it) {
        int4 l = lab4[it * 64 + lane];
        int base = wv * 2048 + it * 256;
#pragma unroll
        for (int cmp = 0; cmp < 4; ++cmp) {
            int li = (cmp == 0) ? l.x : (cmp == 1) ? l.y : (cmp == 2) ? l.z : l.w;
            unsigned long long m = __ballot(li == cls);
            while (m) {                         // wave-uniform loop, ~2 rows/wave avg
                int bb = __builtin_ctzll(m);
                m &= m - 1;
                int row = base + 4 * bb + cmp;
                float2 v = ((const float2*)emb)[row * 64 + lane];
                float ss = fmaf(v.x, v.x, v.y * v.y);
#pragma unroll
                for (int mm = 1; mm < 64; mm <<= 1) ss += __shfl_xor(ss, mm, 64);
                float inv = 1.0f / fmaxf(sqrtf(ss), 1e-12f);
                bf16x2 o; o.x = (bf16_t)(v.x * inv); o.y = (bf16_t)(v.y * inv);
                *(bf16x2*)(xsw + swz(row, lane)) = o;
                s0 += (float)o.x; s1 += (float)o.y;     // bf16-rounded, matches MFMA
                if (lane == 0) {
                    int idx = atomicAdd(&nrows, 1);
                    if (idx < 96) rowlist[idx] = row;
                }
            }
        }
    }
    atomicAdd(&cs[2 * lane], s0);
    atomicAdd(&cs[2 * lane + 1], s1);
    __syncthreads();
    int n = nrows;
    for (int k = wv; k < n; k += 4) {          // per-row cd/sd (rows split over waves)
        int row = rowlist[k];
        bf16x2 xv = *(const bf16x2*)(xsw + swz(row, lane));
        float x0 = (float)xv.x, x1 = (float)xv.y;
        float cdp = fmaf(x0, cs[2 * lane], x1 * cs[2 * lane + 1]);
        float sdp = fmaf(x0, x0, x1 * x1);
#pragma unroll
        for (int mm = 1; mm < 64; mm <<= 1) {
            cdp += __shfl_xor(cdp, mm, 64);
            sdp += __shfl_xor(sdp, mm, 64);
        }
        if (lane == 0) {
            cd_arr[row] = cdp; sd_arr[row] = sdp; cm1_arr[row] = (float)(n - 1);
        }
    }
}

// --- main: block = (cq, g): 128-col chunk staged to LDS once; wave wv -> row
// band I = 4g+wv (I <= 4cq+3). C layout (m74/m101): col = lane&31,
// row = (r&3) + 8*(r>>2) + 4*(lane>>5).
// Last block to finish (device completion counter) runs the finalize pass.
// NO per-block fences: all published values are device-scope atomics, and
// __syncthreads() drains vmcnt before the counter bump.
__global__ __launch_bounds__(256, 4) void supcon_main(const bf16_t* __restrict__ xsw,
                                                      float* __restrict__ se_acc,
                                                      const float* __restrict__ cd_arr,
                                                      const float* __restrict__ sd_arr,
                                                      const float* __restrict__ cm1_arr,
                                                      int* __restrict__ done_cnt,
                                                      float* __restrict__ out) {
    __shared__ bf16_t bst[4 * 4096];           // 32 KB: the 4 shared B tiles
    __shared__ float cols[128];
    __shared__ int lastflag;
    __shared__ float part[4];
    if (threadIdx.x < 128) cols[threadIdx.x] = 0.f;

    int b = blockIdx.x;                        // triangular decode
    int cq = (int)((sqrtf(8.f * (float)b + 1.f) - 1.f) * 0.5f);
    while ((cq + 1) * (cq + 2) / 2 <= b) ++cq;
    while (cq * (cq + 1) / 2 > b) --cq;
    int g = b - cq * (cq + 1) / 2;

    int wv = threadIdx.x >> 6, lane = threadIdx.x & 63;
    int I = 4 * g + wv;
    int c = lane & 31, h = lane >> 5;
    int laneoff = h * 256 + c * 8;

    // A frags (global, per wave) — issued before staging so latencies overlap
    const bf16_t* abase = xsw + (size_t)I * 4096 + laneoff;
    bf16x8 a[8];
#pragma unroll
    for (int f = 0; f < 8; ++f) a[f] = *(const bf16x8*)(abase + f * 512);

    // stage B chunk (32 KB) once for all 4 waves
    {
        const uint4* gsrc = (const uint4*)(xsw + (size_t)cq * 4 * 4096);
        uint4* ldst = (uint4*)bst;
#pragma unroll
        for (int i = 0; i < 8; ++i)
            ldst[i * 256 + threadIdx.x] = gsrc[i * 256 + threadIdx.x];
    }
    __syncthreads();

    float se[16];
#pragma unroll
    for (int r = 0; r < 16; ++r) se[r] = 0.f;
    float colacc[4] = {0.f, 0.f, 0.f, 0.f};

#pragma unroll
    for (int t = 0; t < 4; ++t) {
        const bf16_t* bt = bst + t * 4096 + laneoff;
        bf16x8 bfr[8];
#pragma unroll
        for (int f = 0; f < 8; ++f) bfr[f] = *(const bf16x8*)(bt + f * 512);
        f32x16 acc;
#pragma unroll
        for (int r = 0; r < 16; ++r) acc[r] = 0.f;
#pragma unroll
        for (int f = 0; f < 8; ++f)
            acc = __builtin_amdgcn_mfma_f32_32x32x16_bf16(a[f], bfr[f], acc, 0, 0, 0);
        int ct = cq * 4 + t;
        if (ct >= I) {                          // wave-uniform mask
            float c0 = 0.f, c1 = 0.f, c2 = 0.f, c3 = 0.f;
#pragma unroll
            for (int r = 0; r < 16; ++r) {
                float e = __builtin_amdgcn_exp2f(fmaf(acc[r], L2E10, -L2E10));
                se[r] += e;
                if ((r & 3) == 0) c0 += e; else if ((r & 3) == 1) c1 += e;
                else if ((r & 3) == 2) c2 += e; else c3 += e;
            }
            if (ct > I) colacc[t] = (c0 + c1) + (c2 + c3);
        }
    }

    // row-side: DPP half-wave reduce (VALU pipe, not DS); sums land in lanes
    // 31 (h=0) and 63 (h=1), which emit the atomics.
#pragma unroll
    for (int r = 0; r < 16; ++r) se[r] = half32_sum(se[r]);
    if (c == 31) {
        int rowbase = I * 32 + 4 * h;
#pragma unroll
        for (int r = 0; r < 16; ++r)
            atomicAdd(&se_acc[rowbase + (r & 3) + 8 * (r >> 2)], se[r]);
    }

    // col-side: combine halves, LDS-combine 4 waves (same cq), flush once
#pragma unroll
    for (int t = 0; t < 4; ++t) {
        float v = colacc[t] + __shfl_xor(colacc[t], 32, 64);
        if (h == 0) atomicAdd(&cols[t * 32 + c], v);
    }
    __syncthreads();
    if (threadIdx.x < 128)
        atomicAdd(&se_acc[cq * 128 + threadIdx.x], cols[threadIdx.x]);

    // ---- fused finalize: last block to retire computes the loss sum ----
    // __syncthreads() drains vmcnt(0) for all waves -> all our se_acc atomics
    // are performed at the device-coherent point before the counter bump.
    __syncthreads();
    if (threadIdx.x == 0) {
        int prev = __hip_atomic_fetch_add(done_cnt, 1, __ATOMIC_RELAXED,
                                          __HIP_MEMORY_SCOPE_AGENT);
        lastflag = (prev == MAIN_BLOCKS - 1) ? 1 : 0;
    }
    __syncthreads();
    if (lastflag == 0) return;
    // single acquire fence (one block, once) + cache-bypassing se_acc loads
    __builtin_amdgcn_fence(__ATOMIC_ACQUIRE, "agent");

    float total = 0.f;
#pragma unroll 4
    for (int k = 0; k < 32; ++k) {
        int i = (k << 8) + threadIdx.x;        // coalesced
        float sd = sd_arr[i], cd = cd_arr[i], cm1 = cm1_arr[i];
        float sev_raw = __hip_atomic_load(&se_acc[i], __ATOMIC_RELAXED,
                                          __HIP_MEMORY_SCOPE_AGENT);
        float diag = __builtin_amdgcn_exp2f(fmaf(sd, L2E10, -L2E10));
        float sev  = fmaxf(sev_raw - diag, 1e-30f);
        float lse  = fmaf(__builtin_amdgcn_logf(sev), LN2, 10.f);   // v_log = log2
        total += (cm1 * lse - 10.f * (cd - sd)) / (cm1 + SMALL_VAL);
    }
#pragma unroll
    for (int m = 1; m < 64; m <<= 1) total += __shfl_xor(total, m, 64);
    if (lane == 0) part[wv] = total;
    __syncthreads();
    if (threadIdx.x == 0) *out = part[0] + part[1] + part[2] + part[3];
}

extern "C" void kernel_launch(void* const* d_in, const int* in_sizes, int n_in,
                              void* d_out, int out_size, void* d_ws, size_t ws_size,
                              hipStream_t stream) {
    const float* emb  = (const float*)d_in[0];
    const int* labels = (const int*)d_in[1];

    char* ws = (char*)d_ws;
    bf16_t* xsw = (bf16_t*)ws;                          // 2 MB swizzled normalized X
    float* se   = (float*)(ws + (size_t)NN * DIM * 2);  // 32 KB
    float* cd   = se + NN;                              // 32 KB
    float* sd   = cd + NN;                              // 32 KB
    float* cm1  = sd + NN;                              // 32 KB
    int* done   = (int*)(cm1 + NN);                     // 4 B completion counter

    norm_csum<<<1024, 256, 0, stream>>>(emb, labels, xsw, cd, sd, cm1, se, done);
    supcon_main<<<MAIN_BLOCKS, 256, 0, stream>>>(xsw, se, cd, sd, cm1, done, (float*)d_out);
}

// Round 4
// 112.629 us; speedup vs baseline: 1.8991x; 1.0029x over previous
//
#include <hip/hip_runtime.h>
#include <hip/hip_bf16.h>

// SupCon loss, N=8192, D=128, T=0.1.
// R9: de-fuse (back to 3 kernels; R6/R8 fusion cost more than the launch it
// saved) and attack supcon_main itself, which the one-fill-per-iteration
// model shows was ~44us all along (MfmaUtil 6.7%, 85% stalled):
//  (1) dual MFMA accumulator chains (evens/odds) -> halves the 8-deep
//      dependent-MFMA critical path per tile,
//  (2) register prefetch of tile t+1's B frags before tile t's MFMA chain,
//  (3) staging via global_load_lds width=16 (dest is linear) -> no VGPR
//      round-trip,
//  (4) cols LDS combine dropped (direct col atomics after half-shuffle):
//      LDS = exactly 32768 B -> 5 blocks/CU (5*32768 = 160KiB), one fewer
//      barrier; __launch_bounds__(256,5).
//
// Math: loss_i = (cm1_i*lse_i - 10*(cd_i - sd_i))/(cm1_i+tiny)
//   lse_i = 10 + ln(sum_{j!=i} e^{s_ij-10})  (constant shift exact; s<=10)
//   cd_i = x_i . classsum[lab_i], sd_i = x_i . x_i (bf16-rounded inputs,
//   consistent with the MFMA path). se accumulated INCLUDING diagonal;
//   diag e^{10*sd-10} subtracted in finalize.
//   Symmetry: tile (I,ct), ct>I feeds rows AND cols; ct==I rows only.

typedef __bf16 bf16_t;
typedef __bf16 bf16x2 __attribute__((ext_vector_type(2)));
typedef __bf16 bf16x8 __attribute__((ext_vector_type(8)));
typedef float f32x16 __attribute__((ext_vector_type(16)));

#define NN 8192
#define DIM 128
#define MAIN_BLOCKS 2080          // sum_{cq=0}^{63} (cq+1)
#define SMALL_VAL 1.17549435e-38f
#define L2E10 14.4269504089f      // 10*log2(e)
#define LN2 0.69314718056f

// Swizzle: X[row][d] at (row>>5)*4096 + (d>>4)*512 + ((d>>3)&1)*256 + (row&31)*8 + (d&7)
// Lane l holds dims (2l, 2l+1): f=l>>3, hh=(l>>2)&1, j=(l&3)*2 (pair contiguous).
__device__ inline size_t swz(int row, int lane) {
    int f = lane >> 3, hh = (lane >> 2) & 1, j = (lane & 3) << 1;
    return ((size_t)(row >> 5) * 4096) + f * 512 + hh * 256 + (row & 31) * 8 + j;
}

// DPP-add step: v += dpp_perm(v). bound_ctrl=1 -> OOB lanes read 0.
#define DPPADD(v, ctrl, rmask)                                                         \
    do {                                                                               \
        int _t = __builtin_amdgcn_update_dpp(0, __float_as_int((v)), (ctrl), (rmask),  \
                                             0xf, true);                               \
        (v) += __int_as_float(_t);                                                     \
    } while (0)

// Sum over each 32-lane half; result valid in lane 31 (h=0) and lane 63 (h=1).
__device__ inline float half32_sum(float v) {
    DPPADD(v, 0x111, 0xf);   // row_shr:1
    DPPADD(v, 0x112, 0xf);   // row_shr:2
    DPPADD(v, 0x114, 0xf);   // row_shr:4
    DPPADD(v, 0x118, 0xf);   // row_shr:8  -> lane 15+16k has 16-lane row sum
    DPPADD(v, 0x142, 0xa);   // row_bcast:15 into rows 1,3 -> lanes 31/63 full
    return v;
}

// async global->LDS, 16B per lane; LDS dest = uniform base + lane*16.
__device__ inline void gload_lds16(const bf16_t* g, bf16_t* l) {
    __builtin_amdgcn_global_load_lds(
        (const __attribute__((address_space(1))) unsigned int*)g,
        (__attribute__((address_space(3))) unsigned int*)l, 16, 0, 0);
}

// --- fused normalize + class-sum + per-row finalize scalars ---
__global__ __launch_bounds__(256) void norm_csum(const float* __restrict__ emb,
                                                 const int* __restrict__ labels,
                                                 bf16_t* __restrict__ xsw,
                                                 float* __restrict__ cd_arr,
                                                 float* __restrict__ sd_arr,
                                                 float* __restrict__ cm1_arr,
                                                 float* __restrict__ se_acc,
                                                 float* __restrict__ out) {
    __shared__ float cs[DIM];
    __shared__ int rowlist[96];
    __shared__ int nrows;
    int cls = blockIdx.x;                      // 1024 blocks; labels < 1000
    int wv = threadIdx.x >> 6, lane = threadIdx.x & 63;
    if (threadIdx.x < DIM) cs[threadIdx.x] = 0.f;
    if (threadIdx.x == 0) nrows = 0;
    if (threadIdx.x < 8) se_acc[cls * 8 + threadIdx.x] = 0.f;   // zero all 8192
    if (cls == 0 && threadIdx.x == 0) *out = 0.f;
    __syncthreads();

    float s0 = 0.f, s1 = 0.f;
    const int4* lab4 = (const int4*)(labels + wv * 2048);       // wave's quarter
#pragma unroll
    for (int it = 0; it < 8; ++it) {
        int4 l = lab4[it * 64 + lane];
        int base = wv * 2048 + it * 256;
#pragma unroll
        for (int cmp = 0; cmp < 4; ++cmp) {
            int li = (cmp == 0) ? l.x : (cmp == 1) ? l.y : (cmp == 2) ? l.z : l.w;
            unsigned long long m = __ballot(li == cls);
            while (m) {                         // wave-uniform loop, ~2 rows/wave avg
                int bb = __builtin_ctzll(m);
                m &= m - 1;
                int row = base + 4 * bb + cmp;
                float2 v = ((const float2*)emb)[row * 64 + lane];
                float ss = fmaf(v.x, v.x, v.y * v.y);
#pragma unroll
                for (int mm = 1; mm < 64; mm <<= 1) ss += __shfl_xor(ss, mm, 64);
                float inv = 1.0f / fmaxf(sqrtf(ss), 1e-12f);
                bf16x2 o; o.x = (bf16_t)(v.x * inv); o.y = (bf16_t)(v.y * inv);
                *(bf16x2*)(xsw + swz(row, lane)) = o;
                s0 += (float)o.x; s1 += (float)o.y;     // bf16-rounded, matches MFMA
                if (lane == 0) {
                    int idx = atomicAdd(&nrows, 1);
                    if (idx < 96) rowlist[idx] = row;
                }
            }
        }
    }
    atomicAdd(&cs[2 * lane], s0);
    atomicAdd(&cs[2 * lane + 1], s1);
    __syncthreads();
    int n = nrows;
    for (int k = wv; k < n; k += 4) {          // per-row cd/sd (rows split over waves)
        int row = rowlist[k];
        bf16x2 xv = *(const bf16x2*)(xsw + swz(row, lane));
        float x0 = (float)xv.x, x1 = (float)xv.y;
        float cdp = fmaf(x0, cs[2 * lane], x1 * cs[2 * lane + 1]);
        float sdp = fmaf(x0, x0, x1 * x1);
#pragma unroll
        for (int mm = 1; mm < 64; mm <<= 1) {
            cdp += __shfl_xor(cdp, mm, 64);
            sdp += __shfl_xor(sdp, mm, 64);
        }
        if (lane == 0) {
            cd_arr[row] = cdp; sd_arr[row] = sdp; cm1_arr[row] = (float)(n - 1);
        }
    }
}

// --- main: block = (cq, g): 128-col chunk staged to LDS once; wave wv -> row
// band I = 4g+wv (I <= 4cq+3). C layout (m74/m101): col = lane&31,
// row = (r&3) + 8*(r>>2) + 4*(lane>>5).
__global__ __launch_bounds__(256, 5) void supcon_main(const bf16_t* __restrict__ xsw,
                                                      float* __restrict__ se_acc) {
    __shared__ bf16_t bst[4 * 4096];           // exactly 32 KB -> 5 blocks/CU

    int b = blockIdx.x;                        // triangular decode
    int cq = (int)((sqrtf(8.f * (float)b + 1.f) - 1.f) * 0.5f);
    while ((cq + 1) * (cq + 2) / 2 <= b) ++cq;
    while (cq * (cq + 1) / 2 > b) --cq;
    int g = b - cq * (cq + 1) / 2;

    int wv = threadIdx.x >> 6, lane = threadIdx.x & 63;
    int I = 4 * g + wv;
    int c = lane & 31, h = lane >> 5;
    int laneoff = h * 256 + c * 8;

    // A frags (global, per wave) — issued before staging so latencies overlap
    const bf16_t* abase = xsw + (size_t)I * 4096 + laneoff;
    bf16x8 a[8];
#pragma unroll
    for (int f = 0; f < 8; ++f) a[f] = *(const bf16x8*)(abase + f * 512);

    // stage B chunk (32 KB) once for all 4 waves: async global->LDS, 16B/lane.
    // Chunk k (1 KB) handled by wave k&3: lds = bst + k*512 (bf16), global
    // = gsrc + k*512 + lane*8; HW writes lds_base + lane*16.
    {
        const bf16_t* gsrc = xsw + (size_t)cq * 4 * 4096;
#pragma unroll
        for (int i = 0; i < 8; ++i) {
            int k = i * 4 + wv;
            gload_lds16(gsrc + k * 512 + lane * 8, bst + k * 512);
        }
    }
    __syncthreads();                           // drains vmcnt -> LDS ready

    float se[16];
#pragma unroll
    for (int r = 0; r < 16; ++r) se[r] = 0.f;

    // tile-0 B frags
    bf16x8 cur[8], nxt[8];
#pragma unroll
    for (int f = 0; f < 8; ++f) cur[f] = *(const bf16x8*)(bst + laneoff + f * 512);

#pragma unroll
    for (int t = 0; t < 4; ++t) {
        // prefetch next tile's frags under this tile's MFMA+exp
        if (t < 3) {
            const bf16_t* btn = bst + (t + 1) * 4096 + laneoff;
#pragma unroll
            for (int f = 0; f < 8; ++f) nxt[f] = *(const bf16x8*)(btn + f * 512);
        }
        // dual accumulator chains: halves the dependent-MFMA critical path
        f32x16 acc0, acc1;
#pragma unroll
        for (int r = 0; r < 16; ++r) { acc0[r] = 0.f; acc1[r] = 0.f; }
#pragma unroll
        for (int f = 0; f < 8; f += 2) {
            acc0 = __builtin_amdgcn_mfma_f32_32x32x16_bf16(a[f], cur[f], acc0, 0, 0, 0);
            acc1 = __builtin_amdgcn_mfma_f32_32x32x16_bf16(a[f + 1], cur[f + 1], acc1, 0, 0, 0);
        }
        int ct = cq * 4 + t;
        if (ct >= I) {                          // wave-uniform mask
            float c0 = 0.f, c1 = 0.f, c2 = 0.f, c3 = 0.f;
#pragma unroll
            for (int r = 0; r < 16; ++r) {
                float s = acc0[r] + acc1[r];
                float e = __builtin_amdgcn_exp2f(fmaf(s, L2E10, -L2E10));
                se[r] += e;
                if ((r & 3) == 0) c0 += e; else if ((r & 3) == 1) c1 += e;
                else if ((r & 3) == 2) c2 += e; else c3 += e;
            }
            if (ct > I) {                       // col-side: halves-combine, direct atomic
                float v = (c0 + c1) + (c2 + c3);
                v += __shfl_xor(v, 32, 64);
                if (h == 0) atomicAdd(&se_acc[ct * 32 + c], v);
            }
        }
        if (t < 3) {
#pragma unroll
            for (int f = 0; f < 8; ++f) cur[f] = nxt[f];
        }
    }

    // row-side: DPP half-wave reduce (VALU pipe, not DS); sums land in lanes
    // 31 (h=0) and 63 (h=1), which emit the atomics.
#pragma unroll
    for (int r = 0; r < 16; ++r) se[r] = half32_sum(se[r]);
    if (c == 31) {
        int rowbase = I * 32 + 4 * h;
#pragma unroll
        for (int r = 0; r < 16; ++r)
            atomicAdd(&se_acc[rowbase + (r & 3) + 8 * (r >> 2)], se[r]);
    }
}

// --- finalize: elementwise loss from precomputed scalars, block reduce ---
__global__ __launch_bounds__(256) void finalize_kernel(const float* __restrict__ se_acc,
                                                       const float* __restrict__ cd_arr,
                                                       const float* __restrict__ sd_arr,
                                                       const float* __restrict__ cm1_arr,
                                                       float* __restrict__ out) {
    __shared__ float part[4];
    int i = blockIdx.x * 256 + threadIdx.x;
    float sd = sd_arr[i], cd = cd_arr[i], cm1 = cm1_arr[i];
    float diag = __builtin_amdgcn_exp2f(fmaf(sd, L2E10, -L2E10));
    float sev  = fmaxf(se_acc[i] - diag, 1e-30f);
    float lse  = fmaf(__builtin_amdgcn_logf(sev), LN2, 10.f);   // v_log = log2
    float loss = (cm1 * lse - 10.f * (cd - sd)) / (cm1 + SMALL_VAL);
#pragma unroll
    for (int m = 1; m < 64; m <<= 1) loss += __shfl_xor(loss, m, 64);
    int wv = threadIdx.x >> 6;
    if ((threadIdx.x & 63) == 0) part[wv] = loss;
    __syncthreads();
    if (threadIdx.x == 0) atomicAdd(out, part[0] + part[1] + part[2] + part[3]);
}

extern "C" void kernel_launch(void* const* d_in, const int* in_sizes, int n_in,
                              void* d_out, int out_size, void* d_ws, size_t ws_size,
                              hipStream_t stream) {
    const float* emb  = (const float*)d_in[0];
    const int* labels = (const int*)d_in[1];

    char* ws = (char*)d_ws;
    bf16_t* xsw = (bf16_t*)ws;                          // 2 MB swizzled normalized X
    float* se   = (float*)(ws + (size_t)NN * DIM * 2);  // 32 KB
    float* cd   = se + NN;                              // 32 KB
    float* sd   = cd + NN;                              // 32 KB
    float* cm1  = sd + NN;                              // 32 KB

    norm_csum<<<1024, 256, 0, stream>>>(emb, labels, xsw, cd, sd, cm1, se, (float*)d_out);
    supcon_main<<<MAIN_BLOCKS, 256, 0, stream>>>(xsw, se);
    finalize_kernel<<<NN / 256, 256, 0, stream>>>(se, cd, sd, cm1, (float*)d_out);
}